// Round 6
// baseline (298.687 us; speedup 1.0000x reference)
//
#include <hip/hip_runtime.h>
#include <hip/hip_bf16.h>

#define N_ 100000
#define E_ 1600000
#define D_ 128
#define H_ 4
#define C_ 32
#define CAP 64    // per-node bucket capacity; deg ~ Poisson(16), P(deg>64) ~ 1e-18
#define XSTR 136  // padded LDS row stride (shorts): 272 B
#define NBUILD 256   // builder blocks (bid%3==0)
#define NLIN 512     // linear blocks

using bf16 = __hip_bfloat16;
typedef __attribute__((ext_vector_type(8))) short short8;
typedef __attribute__((ext_vector_type(4))) float f32x4;
typedef __attribute__((ext_vector_type(2))) float f32x2;

__device__ __forceinline__ float u2f(unsigned u) { return __uint_as_float(u); }
__device__ __forceinline__ unsigned short f2bu(float v) {
  bf16 t = __float2bfloat16(v);
  return *(unsigned short*)&t;
}

// ---------------------------------------------------------------------------
// Fused kernel: block-role specialization. Builder blocks (256) stream the
// 1.6M edge scatter (fabric-atomic-rate-bound, ~0% VALU) CONCURRENTLY with
// linear blocks (512) doing the MFMA x@W^T (+attention logits).
// ---------------------------------------------------------------------------
__global__ __launch_bounds__(256) void k_build_linear(
    const float* __restrict__ x, const float* __restrict__ W,
    const float* __restrict__ att_src, const float* __restrict__ att_dst,
    const int* __restrict__ ei, int* __restrict__ cnt, int* __restrict__ slot,
    bf16* __restrict__ h, float* __restrict__ a_src, float* __restrict__ a_dst) {
  __shared__ unsigned short WB[16384];      // 32 KB, pre-swizzled B fragments
  __shared__ unsigned short XS[64 * XSTR];  // 17 KB, wave-private epilogue
  __shared__ float ats[128], atd[128];
  const int tid = threadIdx.x;
  const int bid = blockIdx.x;
  const int role = bid % 3;

  if (role == 0) {
    // ---- builder role: grid-stride over E, 4 independent edges in flight
    const int bb = bid / 3;  // 0..255
    for (int base = bb * 1024; base < E_; base += NBUILD * 1024) {
      const int e0 = base + tid;
      const int e1 = base + 256 + tid;
      const int e2 = base + 512 + tid;
      const int e3 = base + 768 + tid;
      int d0 = 0, d1 = 0, d2 = 0, d3 = 0, s0 = 0, s1 = 0, s2 = 0, s3 = 0;
      if (e0 < E_) { d0 = ei[E_ + e0]; s0 = ei[e0]; }
      if (e1 < E_) { d1 = ei[E_ + e1]; s1 = ei[e1]; }
      if (e2 < E_) { d2 = ei[E_ + e2]; s2 = ei[e2]; }
      if (e3 < E_) { d3 = ei[E_ + e3]; s3 = ei[e3]; }
      if (e0 < E_) { const int p = atomicAdd(&cnt[d0], 1); if (p < CAP) slot[d0 * CAP + p] = s0; }
      if (e1 < E_) { const int p = atomicAdd(&cnt[d1], 1); if (p < CAP) slot[d1 * CAP + p] = s1; }
      if (e2 < E_) { const int p = atomicAdd(&cnt[d2], 1); if (p < CAP) slot[d2 * CAP + p] = s2; }
      if (e3 < E_) { const int p = atomicAdd(&cnt[d3], 1); if (p < CAP) slot[d3 * CAP + p] = s3; }
    }
    return;
  }

  // ---- linear role
  const int lb = (bid / 3) * 2 + (role - 1);  // 0..511
  const int lane = tid & 63, w = tid >> 6;
  const int n15 = lane & 15, quad = lane >> 4;

  for (int i = tid; i < 16384; i += 256) {
    const int n = i >> 7, k = i & 127;
    const int kk = k >> 5, q = (k >> 3) & 3, j = k & 7;
    const int frag = kk * 8 + (n >> 4);
    WB[frag * 512 + q * 128 + (n & 15) * 8 + j] = f2bu(W[n * 128 + k]);
  }
  if (tid < 128) { ats[tid] = att_src[tid]; atd[tid] = att_dst[tid]; }
  __syncthreads();  // one-time publish; main loop is barrier-free

  const int nrb = (N_ + 63) / 64;  // 1563
  for (int rb = lb; rb < nrb; rb += NLIN) {
    const int row0 = rb * 64;
    const int arow = row0 + w * 16 + n15;

    // A fragments straight from x: lane (n15,quad) needs x[arow][kk*32+quad*8+0..7]
    short8 af[4];
#pragma unroll
    for (int kk = 0; kk < 4; kk++) {
      float4 p = make_float4(0.f, 0.f, 0.f, 0.f);
      float4 q = make_float4(0.f, 0.f, 0.f, 0.f);
      if (arow < N_) {
        const float* xp = &x[(size_t)arow * 128 + kk * 32 + quad * 8];
        p = *(const float4*)xp;
        q = *(const float4*)(xp + 4);
      }
      short8 a;
      a[0] = f2bu(p.x); a[1] = f2bu(p.y); a[2] = f2bu(p.z); a[3] = f2bu(p.w);
      a[4] = f2bu(q.x); a[5] = f2bu(q.y); a[6] = f2bu(q.z); a[7] = f2bu(q.w);
      af[kk] = a;
    }

    f32x4 acc[8] = {};
#pragma unroll
    for (int kk = 0; kk < 4; kk++)
#pragma unroll
      for (int t = 0; t < 8; t++) {
        const short8 b = *(const short8*)&WB[(kk * 8 + t) * 512 + lane * 8];
        acc[t] = __builtin_amdgcn_mfma_f32_16x16x32_bf16(af[kk], b, acc[t], 0, 0, 0);
      }

    // wave-private transpose: wave w owns XS rows w*16 .. w*16+15
#pragma unroll
    for (int t = 0; t < 8; t++)
#pragma unroll
      for (int reg = 0; reg < 4; reg++)
        XS[(w * 16 + quad * 4 + reg) * XSTR + t * 16 + n15] = f2bu(acc[t][reg]);

    // same-wave readback (compiler inserts lgkm waits; DS ops are wave-ordered)
    const int lrow = lane >> 2, hd = lane & 3, cb = hd * 32;
    const int grow = row0 + w * 16 + lrow;
    if (grow < N_) {
      float ps = 0.f, pd = 0.f;
#pragma unroll
      for (int g = 0; g < 4; g++) {
        const uint4 v = *(const uint4*)&XS[(w * 16 + lrow) * XSTR + cb + g * 8];
        *(uint4*)&h[(size_t)grow * 128 + cb + g * 8] = v;
        const unsigned uu[4] = {v.x, v.y, v.z, v.w};
#pragma unroll
        for (int p2 = 0; p2 < 4; p2++) {
          const float f0 = u2f(uu[p2] << 16);
          const float f1 = u2f(uu[p2] & 0xffff0000u);
          const int cc = cb + g * 8 + p2 * 2;
          ps = fmaf(f0, ats[cc], ps);  ps = fmaf(f1, ats[cc + 1], ps);
          pd = fmaf(f0, atd[cc], pd);  pd = fmaf(f1, atd[cc + 1], pd);
        }
      }
      a_src[grow * 4 + hd] = ps;
      a_dst[grow * 4 + hd] = pd;
    }
  }
}

// ---------------------------------------------------------------------------
// Kernel 2: gather, 4 edges per iteration. Lanes = 4 edge-groups x 16
// channel-lanes (8 ch each). Per iteration each group handles its own edge:
// w computed with 4x (not 16x) redundancy, one VMEM covers 4 h-fragments.
// Cross-group shfl_xor reduce + LDS redistribution back to 2 ch/lane for the
// LN/gelu epilogue (all 64 lanes share the erf work).
// ---------------------------------------------------------------------------
__global__ __launch_bounds__(256) void k_gather(
    const int* __restrict__ cnt, const int* __restrict__ slot,
    const float* __restrict__ a_src, const float* __restrict__ a_dst,
    const bf16* __restrict__ h, const float* __restrict__ bias,
    const float* __restrict__ gamma, const float* __restrict__ beta,
    float* __restrict__ out) {
  __shared__ float RED[4][128];
  const int tid = threadIdx.x;
  const int lane = tid & 63;
  const int wid = tid >> 6;
  const int d = blockIdx.x * 4 + wid;
  if (d >= N_) return;
  const int g = lane >> 4;    // edge-group 0..3
  const int l16 = lane & 15;  // channel-lane 0..15 (8 ch each)
  const int headp = l16 >> 2; // head owning my 8 producer channels
  const int ch0 = l16 * 8;
  const int deg0 = cnt[d];
  const int deg = deg0 < CAP ? deg0 : CAP;
  const float ad = a_dst[d * 4 + headp];
  const int* __restrict__ srow = slot + (size_t)d * CAP;

  int my_src = 0;
  if (lane < deg) my_src = srow[lane];  // whole edge list, one coalesced load

  float acc[8] = {0.f, 0.f, 0.f, 0.f, 0.f, 0.f, 0.f, 0.f};
  float sumw = 0.f;

  for (int base = 0; base < deg; base += 4) {
    const int idx = base + g;
    const bool live = idx < deg;
    const int s = __shfl(my_src, live ? idx : 0);
    float ev = a_src[s * 4 + headp] + ad;
    ev = (ev > 0.f) ? ev : 0.2f * ev;
    const float w = live ? __expf(ev) : 0.f;
    sumw += w;
    const uint4 hv = *(const uint4*)&h[((size_t)s << 7) + ch0];  // 16B fragment
    const unsigned uu[4] = {hv.x, hv.y, hv.z, hv.w};
#pragma unroll
    for (int p = 0; p < 4; p++) {
      acc[p * 2]     = fmaf(w, u2f(uu[p] << 16), acc[p * 2]);
      acc[p * 2 + 1] = fmaf(w, u2f(uu[p] & 0xffff0000u), acc[p * 2 + 1]);
    }
  }

  // reduce partial sums across the 4 edge-groups
#pragma unroll
  for (int p = 0; p < 8; p++) {
    acc[p] += __shfl_xor(acc[p], 16);
    acc[p] += __shfl_xor(acc[p], 32);
  }
  sumw += __shfl_xor(sumw, 16);
  sumw += __shfl_xor(sumw, 32);

  // normalize + bias in producer layout, publish to LDS (wave-ordered DS)
  const float inv = 1.0f / (sumw + 1e-16f);
  if (g == 0) {
    const float4 b0 = *(const float4*)&bias[ch0];
    const float4 b1 = *(const float4*)&bias[ch0 + 4];
    const float bb[8] = {b0.x, b0.y, b0.z, b0.w, b1.x, b1.y, b1.z, b1.w};
#pragma unroll
    for (int p = 0; p < 8; p++) RED[wid][ch0 + p] = acc[p] * inv + bb[p];
  }
  // same-wave readback at 2 ch/lane (DS ops are wave-ordered within a wave)
  const int ch = lane * 2;
  const float2 vv = *(const float2*)&RED[wid][ch];
  // cos^2+sin^2 == 1 to 1 ulp -> mag = sqrt(v^2 + 1e-12)
  const float m0i = sqrtf(vv.x * vv.x + 1e-12f);
  const float m1i = sqrtf(vv.y * vv.y + 1e-12f);

  float s1r = m0i + m1i;
#pragma unroll
  for (int off = 32; off > 0; off >>= 1) s1r += __shfl_xor(s1r, off);
  const float mu = s1r * (1.0f / 128.0f);
  const float d0 = m0i - mu, d1 = m1i - mu;
  float q = d0 * d0 + d1 * d1;
#pragma unroll
  for (int off = 32; off > 0; off >>= 1) q += __shfl_xor(q, off);
  const float rstd = rsqrtf(q * (1.0f / 128.0f) + 1e-5f);
  const float2 ga = *(const float2*)&gamma[ch];
  const float2 be = *(const float2*)&beta[ch];
  const float hn0 = d0 * rstd * ga.x + be.x;
  const float hn1 = d1 * rstd * ga.y + be.y;
  const float g0 = 0.5f * hn0 * (1.0f + erff(hn0 * 0.70710678118654752f));
  const float g1 = 0.5f * hn1 * (1.0f + erff(hn1 * 0.70710678118654752f));
  f32x2 gv; gv.x = g0; gv.y = g1;
  __builtin_nontemporal_store(gv, (f32x2*)&out[(size_t)d * 128 + ch]);
}

// ---------------------------------------------------------------------------
extern "C" void kernel_launch(void* const* d_in, const int* in_sizes, int n_in,
                              void* d_out, int out_size, void* d_ws, size_t ws_size,
                              hipStream_t stream) {
  const float* x       = (const float*)d_in[0];
  const int*   ei      = (const int*)d_in[1];
  const float* W       = (const float*)d_in[2];
  const float* att_src = (const float*)d_in[3];
  const float* att_dst = (const float*)d_in[4];
  const float* bias    = (const float*)d_in[5];
  const float* gamma   = (const float*)d_in[7];
  const float* beta    = (const float*)d_in[8];
  float* out = (float*)d_out;

  // workspace (54.8 MB)
  bf16*  h     = (bf16*)d_ws;                        // N*128 bf16 (25.6 MB)
  float* a_src = (float*)(h + (size_t)N_ * D_);      // N*4 f32 (1.6 MB)
  float* a_dst = a_src + (size_t)N_ * H_;            // N*4 f32 (1.6 MB)
  int*   cnt   = (int*)(a_dst + (size_t)N_ * H_);    // N int (0.4 MB)
  int*   slot  = cnt + (size_t)N_;                   // N*CAP int (25.6 MB)

  (void)hipMemsetAsync(cnt, 0, (size_t)N_ * sizeof(int), stream);

  k_build_linear<<<768, 256, 0, stream>>>(x, W, att_src, att_dst, ei, cnt,
                                          slot, h, a_src, a_dst);
  k_gather<<<(N_ + 3) / 4, 256, 0, stream>>>(cnt, slot, a_src, a_dst, h,
                                             bias, gamma, beta, out);
}